// Round 12
// baseline (156.326 us; speedup 1.0000x reference)
//
#include <hip/hip_runtime.h>
#include <hip/hip_bf16.h>

// Flash-attention prefill w/ GQA, causal + sliding-window(1024), attention sink.
// B=1, S=2048, Hq=32, Hkv=8, D=128. fp32 in/out; bf16 MFMA compute, fp32 accum.
// R18: counted-vmcnt pipeline (T3/T4) with TLP preserved.
//   R17 post-mortem: ~33% all-wave-stall per SIMD; no pipe saturated. Replace
//   __syncthreads (vmcnt(0)+lgkmcnt(0) drain) with raw s_barrier + counted
//   s_waitcnt: K triple-buffered & staged 2 tiles ahead (its loads stay in
//   flight ACROSS the barrier), V double-buffered 1 ahead. LDS = 40KB ->
//   still 4 blocks/CU = 16 waves/CU (R8/R15 TLP law respected).
//   Sync proof: at top of iter s, FIFO-outstanding = {K(s),V(s) [maybe
//   retired], K(s+1)}; vmcnt(2) retires K(s),V(s) (and prologue Q loads at
//   s=0); barrier then guarantees ALL waves' stage(s) quarters landed and all
//   waves finished reading the buffers that stage(s+1)/(s+2) will overwrite
//   (those reads happened in iter s-1, before the barrier). Last iter uses
//   vmcnt(0). No other vmem ops inside the loop.
// Everything else identical to R17 (fragment-ordered conflict-free LDS,
// register-resident P, swapped QK^T, MFMA denominator, vf preload, setprio,
// dispatch stagger).

#define S_LEN 2048
#define DH    128
#define HQ    32
#define HKV   8
#define WIN   1024
#define BR    64
#define BC    32
#define NT    (S_LEN / BC)          // 64 j-tiles
#define FM    16.0f                 // fixed log2-domain softmax max
#define TILE_CH 512                 // 16B chunks per 32x128 bf16 tile

typedef unsigned short u16;
typedef __attribute__((ext_vector_type(8))) short  short8;
typedef __attribute__((ext_vector_type(4))) float  floatx4;
typedef __attribute__((ext_vector_type(4))) unsigned int uintx4;

__device__ __forceinline__ unsigned rne1(float a) {
    unsigned u = __float_as_uint(a);
    return (u + 0x7FFFu + ((u >> 16) & 1u)) >> 16;
}
__device__ __forceinline__ unsigned rne_pk(float a, float b) {
    return rne1(a) | (rne1(b) << 16);
}
// single-instruction RNE pack (same rounding as rne_pk; validated R8-R17)
__device__ __forceinline__ unsigned cvt_pk(float a, float b) {
    unsigned r;
    asm("v_cvt_pk_bf16_f32 %0, %1, %2" : "=v"(r) : "v"(a), "v"(b));
    return r;
}

// ---------------- pre-pass: pack K/V^T to bf16 in ws (R14 verbatim) ----------------
// Fragment-ordered layout:
//   K (row, cc):  instr = (row>>4)*4 + (cc>>2), lane = (cc&3)*16 + (row&15)
//   V (dd, c):    instr = dd>>4,               lane = c*16 + (dd&15)
__global__ __launch_bounds__(256) void pack_kv(const float* __restrict__ kg,
                                               const float* __restrict__ vg,
                                               u16* __restrict__ kp,
                                               u16* __restrict__ vtp)
{
    __shared__ float Vs[BC][DH + 1];
    const int b   = blockIdx.x;
    const int hk  = b >> 6;
    const int jt  = b & 63;
    const int tid = threadIdx.x;
    const int j0  = jt * BC;

    #pragma unroll
    for (int t = 0; t < 4; t++) {
        int idx = tid + t * 256;        // float4 id 0..1023
        int j   = idx >> 5;
        int dc  = idx & 31;
        floatx4 f = *(const floatx4*)(vg + ((size_t)(j0 + j) * HKV + hk) * DH + dc * 4);
        Vs[j][dc * 4 + 0] = f[0]; Vs[j][dc * 4 + 1] = f[1];
        Vs[j][dc * 4 + 2] = f[2]; Vs[j][dc * 4 + 3] = f[3];
    }

    u16* kpt = kp + (size_t)b * TILE_CH * 8;
    #pragma unroll
    for (int t = 0; t < 2; t++) {
        int c = tid + t * 256;
        int row = c >> 4, cc = c & 15;
        const float* p = kg + ((size_t)(j0 + row) * HKV + hk) * DH + cc * 8;
        floatx4 f0 = *(const floatx4*)p;
        floatx4 f1 = *(const floatx4*)(p + 4);
        int pc = (((row >> 4) * 4 + (cc >> 2)) << 6) | ((cc & 3) << 4) | (row & 15);
        *(uintx4*)(kpt + pc * 8) =
            (uintx4){rne_pk(f0[0], f0[1]), rne_pk(f0[2], f0[3]),
                     rne_pk(f1[0], f1[1]), rne_pk(f1[2], f1[3])};
    }
    __syncthreads();

    u16* vpt = vtp + (size_t)b * TILE_CH * 8;
    #pragma unroll
    for (int t = 0; t < 2; t++) {
        int q  = tid + t * 256;
        int dd = q >> 2, c = q & 3;
        unsigned w0 = rne_pk(Vs[c * 4 + 0][dd], Vs[c * 4 + 16][dd]);
        unsigned w1 = rne_pk(Vs[c * 4 + 1][dd], Vs[c * 4 + 17][dd]);
        unsigned w2 = rne_pk(Vs[c * 4 + 2][dd], Vs[c * 4 + 18][dd]);
        unsigned w3 = rne_pk(Vs[c * 4 + 3][dd], Vs[c * 4 + 19][dd]);
        int qp = ((dd >> 4) << 6) | (c << 4) | (dd & 15);
        *(uintx4*)(vpt + qp * 8) = (uintx4){w0, w1, w2, w3};
    }
}

// ------ main flash kernel (R18: counted-vmcnt pipeline, 3xK + 2xV buffers) ------
__launch_bounds__(256, 4)
__global__ void fa_kernel(const float* __restrict__ qg,
                          const u16* __restrict__ kp,
                          const u16* __restrict__ vtp,
                          const float* __restrict__ sg,
                          float* __restrict__ outg)
{
    __shared__ __align__(16) u16 Kt[3][TILE_CH * 8];   // 3 x 8 KB (2-deep prefetch)
    __shared__ __align__(16) u16 Vt[2][TILE_CH * 8];   // 2 x 8 KB (1-deep) => 40 KB

    const int tid  = threadIdx.x;
    const int w    = tid >> 6;
    const int lane = tid & 63;
    const int quad = lane >> 4;
    const int l16  = lane & 15;

    // R6 mapping: hk = bid&7 (XCD-local KV); per-CU-slot qb set is balanced.
    const int bid  = blockIdx.x;
    const int hk   = bid & 7;
    const int idx  = bid >> 3;          // 0..127 within this hk
    const int hrem = idx & 3;
    const int u5   = (idx >> 2) & 7;
    const int t4   = idx >> 5;          // 0..3
    const int qbt[4] = {u5, 15 - u5, 16 + u5, 31 - u5};
    const int qb   = qbt[t4];
    const int h    = hk * 4 + hrem;

    // R17: de-phase co-resident blocks (slot = bid>>8); ~slot*384 cyc.
    {
        const int slot = bid >> 8;      // 0..3
        for (int s = 0; s < slot; s++)
            __builtin_amdgcn_s_sleep(6);
    }

    const int i0 = qb * BR;
    const int m0 = i0 + w * 16;

    // ---- Q fragments (B-operand of swapped QK^T) ----
    short8 qf[4];
    {
        const float* qrow = qg + ((size_t)(m0 + l16) * HQ + h) * DH;
        #pragma unroll
        for (int kk = 0; kk < 4; kk++) {
            const float* p = qrow + kk * 32 + quad * 8;
            floatx4 f0 = *(const floatx4*)p;
            floatx4 f1 = *(const floatx4*)(p + 4);
            uintx4 uq = (uintx4){cvt_pk(f0[0], f0[1]), cvt_pk(f0[2], f0[3]),
                                 cvt_pk(f1[0], f1[1]), cvt_pk(f1[2], f1[3])};
            qf[kk] = *(short8*)&uq;
        }
    }

    // ones B-fragment (bf16 1.0 = 0x3F80) for the denominator MFMA
    short8 ones;
    {
        uintx4 uo = (uintx4){0x3F803F80u, 0x3F803F80u, 0x3F803F80u, 0x3F803F80u};
        ones = *(short8*)&uo;
    }

    const int lane8 = lane * 8;         // u16 offset of this lane within a frag row

    floatx4 acc[8];
    #pragma unroll
    for (int i = 0; i < 8; i++) acc[i] = (floatx4){0.f, 0.f, 0.f, 0.f};
    floatx4 acc_l = (floatx4){0.f, 0.f, 0.f, 0.f};   // denominators via MFMA

    const int ci  = m0 + l16;          // this lane's Q row (global index)
    const int qb4 = quad * 4;          // j sub-base within tile

    int jlo = i0 - (WIN - 1); if (jlo < 0) jlo = 0;
    const int jt_lo = jlo >> 5;
    const int jt_hi = (i0 + BR - 1) >> 5;
    const int nt    = jt_hi - jt_lo + 1;   // >= 2 always

    const float SC2 = 0.08838834764831845f * 1.4426950408889634f;

    const int ch0 = w * 64 + lane;
    auto stageK = [&](int b, int jt) {
        const u16* kpt = kp + ((size_t)(hk * NT + jt)) * TILE_CH * 8;
        #pragma unroll
        for (int it = 0; it < 2; it++) {
            int ch = ch0 + it * 256;
            __builtin_amdgcn_global_load_lds(
                (const __attribute__((address_space(1))) unsigned*)(kpt + ch * 8),
                (__attribute__((address_space(3))) unsigned*)(&Kt[b][ch * 8]), 16, 0, 0);
        }
    };
    auto stageV = [&](int b, int jt) {
        const u16* vpt = vtp + ((size_t)(hk * NT + jt)) * TILE_CH * 8;
        #pragma unroll
        for (int it = 0; it < 2; it++) {
            int ch = ch0 + it * 256;
            __builtin_amdgcn_global_load_lds(
                (const __attribute__((address_space(1))) unsigned*)(vpt + ch * 8),
                (__attribute__((address_space(3))) unsigned*)(&Vt[b][ch * 8]), 16, 0, 0);
        }
    };

    // ---- prologue: K 2-deep, V 1-deep ----
    stageK(0, jt_lo);
    stageV(0, jt_lo);
    if (nt > 1) stageK(1, jt_lo + 1);

    int kb = 0, vb = 0;
    for (int s = 0; s < nt; s++) {
        // Retire stage(s) (and prologue Q loads at s=0); K(s+1) stays in flight.
        if (s + 1 < nt) asm volatile("s_waitcnt vmcnt(2)" ::: "memory");
        else            asm volatile("s_waitcnt vmcnt(0)" ::: "memory");
        __builtin_amdgcn_s_barrier();
        __builtin_amdgcn_sched_barrier(0);

        if (s + 1 < nt) stageV(vb ^ 1, jt_lo + s + 1);
        if (s + 2 < nt) stageK(kb == 0 ? 2 : kb - 1, jt_lo + s + 2);

        const int j0 = (jt_lo + s) << 5;

        // ---- swapped QK^T: ss[n][r] = S[j0 + n*16 + qb4 + r][ci], 8 mfma ----
        floatx4 ss[2];
        ss[0] = (floatx4){0.f, 0.f, 0.f, 0.f};
        ss[1] = (floatx4){0.f, 0.f, 0.f, 0.f};
        __builtin_amdgcn_s_setprio(1);
        #pragma unroll
        for (int kk = 0; kk < 4; kk++) {
            short8 kf0 = *(const short8*)(&Kt[kb][(kk << 9) + lane8]);          // instr kk
            short8 kf1 = *(const short8*)(&Kt[kb][((4 + kk) << 9) + lane8]);    // instr 4+kk
            ss[0] = __builtin_amdgcn_mfma_f32_16x16x32_bf16(kf0, qf[kk], ss[0], 0, 0, 0);
            ss[1] = __builtin_amdgcn_mfma_f32_16x16x32_bf16(kf1, qf[kk], ss[1], 0, 0, 0);
        }
        __builtin_amdgcn_s_setprio(0);

        // ---- early V-fragment loads: latency drains under softmax ----
        short8 vf[8];
        #pragma unroll
        for (int nf = 0; nf < 8; nf++)
            vf[nf] = *(const short8*)(&Vt[vb][(nf << 9) + lane8]);

        // ---- softmax (fixed max); P stays in registers ----
        float p[2][4];
        const bool interior = (j0 + (BC - 1) <= i0) && (j0 >= i0 + BR - WIN);
        if (interior) {
            #pragma unroll
            for (int n = 0; n < 2; n++)
                #pragma unroll
                for (int r = 0; r < 4; r++)
                    p[n][r] = exp2f(fmaf(ss[n][r], SC2, -FM));
        } else {
            const int dj = ci - j0;        // allowed: t <= dj && t > dj-WIN
            #pragma unroll
            for (int n = 0; n < 2; n++)
                #pragma unroll
                for (int r = 0; r < 4; r++) {
                    int t = n * 16 + qb4 + r;
                    bool a = (t <= dj) && (t > dj - WIN);
                    p[n][r] = a ? exp2f(fmaf(ss[n][r], SC2, -FM)) : 0.f;
                }
        }

        // ---- P -> A-fragment: interleave chain0/chain1 to match V's k-map ----
        uintx4 upf = (uintx4){cvt_pk(p[0][0], p[1][0]), cvt_pk(p[0][1], p[1][1]),
                              cvt_pk(p[0][2], p[1][2]), cvt_pk(p[0][3], p[1][3])};
        short8 pf = *(short8*)&upf;

        // ---- PV: 8 mfma + 1 denominator mfma (V already in registers) ----
        __builtin_amdgcn_s_setprio(1);
        acc_l = __builtin_amdgcn_mfma_f32_16x16x32_bf16(pf, ones, acc_l, 0, 0, 0);
        #pragma unroll
        for (int nf = 0; nf < 8; nf++) {
            acc[nf] = __builtin_amdgcn_mfma_f32_16x16x32_bf16(pf, vf[nf], acc[nf], 0, 0, 0);
        }
        __builtin_amdgcn_s_setprio(0);

        kb = (kb == 2) ? 0 : kb + 1;
        vb ^= 1;
    }

    // ---- epilogue: denominators already complete in acc_l[r] (no shuffles) ----
    const float sk2 = exp2f(fmaf(sg[h], 1.4426950408889634f, -FM));
    float inv_r[4];
    #pragma unroll
    for (int r = 0; r < 4; r++)
        inv_r[r] = 1.f / (acc_l[r] + sk2);
    #pragma unroll
    for (int nf = 0; nf < 8; nf++) {
        int d = nf * 16 + l16;
        #pragma unroll
        for (int r = 0; r < 4; r++) {
            int ig = m0 + qb4 + r;
            outg[((size_t)ig * HQ + h) * DH + d] = acc[nf][r] * inv_r[r];
        }
    }
}

// ---------------- fallback (used only if ws too small; champion verbatim) --------
__launch_bounds__(256, 4)
__global__ void fa_fallback(const float* __restrict__ qg,
                            const float* __restrict__ kg,
                            const float* __restrict__ vg,
                            const float* __restrict__ sg,
                            float* __restrict__ outg)
{
    __shared__ __align__(16) u16 Kt[BC * DH];
    __shared__ __align__(16) u16 Vt[DH * BC];
    __shared__ __align__(16) u16 Pb[BR * 40];

    const int tid  = threadIdx.x;
    const int w    = tid >> 6;
    const int lane = tid & 63;
    const int quad = lane >> 4;
    const int l16  = lane & 15;

    const int qb = blockIdx.x / HQ;
    const int h  = blockIdx.x % HQ;
    const int hk = h >> 2;
    const int i0 = qb * BR;
    const int m0 = i0 + w * 16;

    short8 qf[4];
    {
        const float* qrow = qg + ((size_t)(m0 + l16) * HQ + h) * DH;
        #pragma unroll
        for (int kk = 0; kk < 4; kk++) {
            const float* p = qrow + kk * 32 + quad * 8;
            floatx4 f0 = *(const floatx4*)p;
            floatx4 f1 = *(const floatx4*)(p + 4);
            uintx4 u = (uintx4){rne_pk(f0[0], f0[1]), rne_pk(f0[2], f0[3]),
                                rne_pk(f1[0], f1[1]), rne_pk(f1[2], f1[3])};
            qf[kk] = *(short8*)&u;
        }
    }

    floatx4 acc[8];
    #pragma unroll
    for (int i = 0; i < 8; i++) acc[i] = (floatx4){0.f, 0.f, 0.f, 0.f};
    float l_part[4] = {0.f, 0.f, 0.f, 0.f};

    int jlo = i0 - (WIN - 1); if (jlo < 0) jlo = 0;
    const int jt_lo = jlo >> 5;
    const int jt_hi = (i0 + BR - 1) >> 5;
    const float SC2 = 0.08838834764831845f * 1.4426950408889634f;

    for (int jt = jt_lo; jt <= jt_hi; jt++) {
        const int j0 = jt << 5;
        __syncthreads();
        #pragma unroll
        for (int it = 0; it < 2; it++) {
            int g   = tid + 256 * it;
            int row = g >> 4, cc = g & 15;
            int pc  = (row << 4) | (cc ^ (row & 7));
            const float* kpp = kg + ((size_t)(j0 + row) * HKV + hk) * DH + cc * 8;
            floatx4 f0 = *(const floatx4*)kpp;
            floatx4 f1 = *(const floatx4*)(kpp + 4);
            *(uintx4*)(&Kt[pc * 8]) =
                (uintx4){rne_pk(f0[0], f0[1]), rne_pk(f0[2], f0[3]),
                         rne_pk(f1[0], f1[1]), rne_pk(f1[2], f1[3])};
        }
        #pragma unroll
        for (int it = 0; it < 2; it++) {
            int g  = tid + 256 * it;
            int d  = g & 127, jc = g >> 7;
            const float* vp = vg + ((size_t)(j0 + jc * 8) * HKV + hk) * DH + d;
            float e0 = vp[0 * HKV * DH], e1 = vp[1 * HKV * DH];
            float e2 = vp[2 * HKV * DH], e3 = vp[3 * HKV * DH];
            float e4 = vp[4 * HKV * DH], e5 = vp[5 * HKV * DH];
            float e6 = vp[6 * HKV * DH], e7 = vp[7 * HKV * DH];
            int pc = (d << 2) | (jc ^ ((d >> 2) & 3));
            *(uintx4*)(&Vt[pc * 8]) =
                (uintx4){rne_pk(e0, e1), rne_pk(e2, e3), rne_pk(e4, e5), rne_pk(e6, e7)};
        }
        __syncthreads();

        floatx4 sc[2];
        sc[0] = (floatx4){0.f, 0.f, 0.f, 0.f};
        sc[1] = (floatx4){0.f, 0.f, 0.f, 0.f};
        #pragma unroll
        for (int kk = 0; kk < 4; kk++) {
            #pragma unroll
            for (int n = 0; n < 2; n++) {
                int row = n * 16 + l16;
                int cc  = kk * 4 + quad;
                int pc  = (row << 4) | (cc ^ (row & 7));
                short8 kf = *(const short8*)(&Kt[pc * 8]);
                sc[n] = __builtin_amdgcn_mfma_f32_16x16x32_bf16(qf[kk], kf, sc[n], 0, 0, 0);
            }
        }
        #pragma unroll
        for (int r = 0; r < 4; r++) {
            int   i_g = m0 + quad * 4 + r;
            int   jg0 = j0 + l16, jg1 = j0 + 16 + l16;
            bool  a0  = (jg0 <= i_g) && (i_g - jg0 < WIN);
            bool  a1  = (jg1 <= i_g) && (i_g - jg1 < WIN);
            float p0  = a0 ? exp2f(fmaf(sc[0][r], SC2, -FM)) : 0.f;
            float p1  = a1 ? exp2f(fmaf(sc[1][r], SC2, -FM)) : 0.f;
            l_part[r] += p0 + p1;
            int prow = w * 16 + quad * 4 + r;
            *(unsigned*)(&Pb[prow * 40 + 2 * l16]) = rne_pk(p0, p1);
        }
        {
            short8 pf = *(const short8*)(&Pb[(w * 16 + l16) * 40 + quad * 8]);
            #pragma unroll
            for (int nf = 0; nf < 8; nf++) {
                int dd = nf * 16 + l16;
                int qp = (dd << 2) | (quad ^ ((dd >> 2) & 3));
                short8 vf = *(const short8*)(&Vt[qp * 8]);
                acc[nf] = __builtin_amdgcn_mfma_f32_16x16x32_bf16(pf, vf, acc[nf], 0, 0, 0);
            }
        }
    }

    const float sk2 = exp2f(fmaf(sg[h], 1.4426950408889634f, -FM));
    float inv[4];
    #pragma unroll
    for (int r = 0; r < 4; r++) {
        float l = l_part[r];
        #pragma unroll
        for (int off = 1; off < 16; off <<= 1)
            l += __shfl_xor(l, off);
        inv[r] = 1.f / (l + sk2);
    }
    #pragma unroll
    for (int nf = 0; nf < 8; nf++) {
        int d = nf * 16 + l16;
        #pragma unroll
        for (int r = 0; r < 4; r++) {
            int ig = m0 + quad * 4 + r;
            outg[((size_t)ig * HQ + h) * DH + d] = acc[nf][r] * inv[r];
        }
    }
}

extern "C" void kernel_launch(void* const* d_in, const int* in_sizes, int n_in,
                              void* d_out, int out_size, void* d_ws, size_t ws_size,
                              hipStream_t stream) {
    const float* q  = (const float*)d_in[0];
    const float* k  = (const float*)d_in[1];
    const float* v  = (const float*)d_in[2];
    const float* sk = (const float*)d_in[3];
    float* out = (float*)d_out;

    const size_t tile_elems = (size_t)HKV * NT * TILE_CH * 8;   // u16 elems per tensor
    const size_t need = 2 * tile_elems * sizeof(u16);           // 8 MB

    if (ws_size >= need) {
        u16* kp  = (u16*)d_ws;
        u16* vtp = kp + tile_elems;
        pack_kv<<<dim3(HKV * NT), 256, 0, stream>>>(k, v, kp, vtp);
        fa_kernel<<<dim3((S_LEN / BR) * HQ), 256, 0, stream>>>(q, kp, vtp, sk, out);
    } else {
        fa_fallback<<<dim3((S_LEN / BR) * HQ), 256, 0, stream>>>(q, k, v, sk, out);
    }
}

// Round 13
// 154.463 us; speedup vs baseline: 1.0121x; 1.0121x over previous
//
#include <hip/hip_runtime.h>
#include <hip/hip_bf16.h>

// Flash-attention prefill w/ GQA, causal + sliding-window(1024), attention sink.
// B=1, S=2048, Hq=32, Hkv=8, D=128. fp32 in/out; bf16 MFMA compute, fp32 accum.
// R19: revert to champion R17 (R18's counted-vmcnt was neutral-to-worse;
// T3/T4 is regime-gated to phase-split schedules, null on 1-phase lockstep).
// R17 = R14 conflict-free fragment-ordered LDS + R13 register-resident P
// (swapped QK^T) + R16 vf-preload/MFMA-denominator/setprio + dispatch-phase
// stagger. Champion measured 52.4-53.7 us (fa_kernel); this resubmission
// confirms reproducibility and locks in the best kernel.

#define S_LEN 2048
#define DH    128
#define HQ    32
#define HKV   8
#define WIN   1024
#define BR    64
#define BC    32
#define NT    (S_LEN / BC)          // 64 j-tiles
#define FM    16.0f                 // fixed log2-domain softmax max
#define TILE_CH 512                 // 16B chunks per 32x128 bf16 tile

typedef unsigned short u16;
typedef __attribute__((ext_vector_type(8))) short  short8;
typedef __attribute__((ext_vector_type(4))) float  floatx4;
typedef __attribute__((ext_vector_type(4))) unsigned int uintx4;

__device__ __forceinline__ unsigned rne1(float a) {
    unsigned u = __float_as_uint(a);
    return (u + 0x7FFFu + ((u >> 16) & 1u)) >> 16;
}
__device__ __forceinline__ unsigned rne_pk(float a, float b) {
    return rne1(a) | (rne1(b) << 16);
}
// single-instruction RNE pack (same rounding as rne_pk; validated R8-R18)
__device__ __forceinline__ unsigned cvt_pk(float a, float b) {
    unsigned r;
    asm("v_cvt_pk_bf16_f32 %0, %1, %2" : "=v"(r) : "v"(a), "v"(b));
    return r;
}

// ---------------- pre-pass: pack K/V^T to bf16 in ws (R14 verbatim) ----------------
// Fragment-ordered layout:
//   K (row, cc):  instr = (row>>4)*4 + (cc>>2), lane = (cc&3)*16 + (row&15)
//   V (dd, c):    instr = dd>>4,               lane = c*16 + (dd&15)
__global__ __launch_bounds__(256) void pack_kv(const float* __restrict__ kg,
                                               const float* __restrict__ vg,
                                               u16* __restrict__ kp,
                                               u16* __restrict__ vtp)
{
    __shared__ float Vs[BC][DH + 1];
    const int b   = blockIdx.x;
    const int hk  = b >> 6;
    const int jt  = b & 63;
    const int tid = threadIdx.x;
    const int j0  = jt * BC;

    #pragma unroll
    for (int t = 0; t < 4; t++) {
        int idx = tid + t * 256;        // float4 id 0..1023
        int j   = idx >> 5;
        int dc  = idx & 31;
        floatx4 f = *(const floatx4*)(vg + ((size_t)(j0 + j) * HKV + hk) * DH + dc * 4);
        Vs[j][dc * 4 + 0] = f[0]; Vs[j][dc * 4 + 1] = f[1];
        Vs[j][dc * 4 + 2] = f[2]; Vs[j][dc * 4 + 3] = f[3];
    }

    u16* kpt = kp + (size_t)b * TILE_CH * 8;
    #pragma unroll
    for (int t = 0; t < 2; t++) {
        int c = tid + t * 256;
        int row = c >> 4, cc = c & 15;
        const float* p = kg + ((size_t)(j0 + row) * HKV + hk) * DH + cc * 8;
        floatx4 f0 = *(const floatx4*)p;
        floatx4 f1 = *(const floatx4*)(p + 4);
        int pc = (((row >> 4) * 4 + (cc >> 2)) << 6) | ((cc & 3) << 4) | (row & 15);
        *(uintx4*)(kpt + pc * 8) =
            (uintx4){rne_pk(f0[0], f0[1]), rne_pk(f0[2], f0[3]),
                     rne_pk(f1[0], f1[1]), rne_pk(f1[2], f1[3])};
    }
    __syncthreads();

    u16* vpt = vtp + (size_t)b * TILE_CH * 8;
    #pragma unroll
    for (int t = 0; t < 2; t++) {
        int q  = tid + t * 256;
        int dd = q >> 2, c = q & 3;
        unsigned w0 = rne_pk(Vs[c * 4 + 0][dd], Vs[c * 4 + 16][dd]);
        unsigned w1 = rne_pk(Vs[c * 4 + 1][dd], Vs[c * 4 + 17][dd]);
        unsigned w2 = rne_pk(Vs[c * 4 + 2][dd], Vs[c * 4 + 18][dd]);
        unsigned w3 = rne_pk(Vs[c * 4 + 3][dd], Vs[c * 4 + 19][dd]);
        int qp = ((dd >> 4) << 6) | (c << 4) | (dd & 15);
        *(uintx4*)(vpt + qp * 8) = (uintx4){w0, w1, w2, w3};
    }
}

// -------- main flash kernel (champion R17: R16 + dispatch-phase stagger) --------
__launch_bounds__(256, 4)
__global__ void fa_kernel(const float* __restrict__ qg,
                          const u16* __restrict__ kp,
                          const u16* __restrict__ vtp,
                          const float* __restrict__ sg,
                          float* __restrict__ outg)
{
    __shared__ __align__(16) u16 Kt[2][TILE_CH * 8];   // 2 x 8 KB
    __shared__ __align__(16) u16 Vt[2][TILE_CH * 8];   // 2 x 8 KB  (total 32 KB)

    const int tid  = threadIdx.x;
    const int w    = tid >> 6;
    const int lane = tid & 63;
    const int quad = lane >> 4;
    const int l16  = lane & 15;

    // R6 mapping: hk = bid&7 (XCD-local KV); per-CU-slot qb set is balanced.
    const int bid  = blockIdx.x;
    const int hk   = bid & 7;
    const int idx  = bid >> 3;          // 0..127 within this hk
    const int hrem = idx & 3;
    const int u5   = (idx >> 2) & 7;
    const int t4   = idx >> 5;          // 0..3
    const int qbt[4] = {u5, 15 - u5, 16 + u5, 31 - u5};
    const int qb   = qbt[t4];
    const int h    = hk * 4 + hrem;

    // R17: de-phase co-resident blocks (slot = bid>>8 under round-robin
    // dispatch at grid 1024 / 256 CUs). slot s sleeps ~s*384 cycles.
    {
        const int slot = bid >> 8;      // 0..3
        for (int s = 0; s < slot; s++)
            __builtin_amdgcn_s_sleep(6);   // ~384 cyc each
    }

    const int i0 = qb * BR;
    const int m0 = i0 + w * 16;

    // ---- Q fragments (B-operand of swapped QK^T) ----
    short8 qf[4];
    {
        const float* qrow = qg + ((size_t)(m0 + l16) * HQ + h) * DH;
        #pragma unroll
        for (int kk = 0; kk < 4; kk++) {
            const float* p = qrow + kk * 32 + quad * 8;
            floatx4 f0 = *(const floatx4*)p;
            floatx4 f1 = *(const floatx4*)(p + 4);
            uintx4 uq = (uintx4){cvt_pk(f0[0], f0[1]), cvt_pk(f0[2], f0[3]),
                                 cvt_pk(f1[0], f1[1]), cvt_pk(f1[2], f1[3])};
            qf[kk] = *(short8*)&uq;
        }
    }

    // ones B-fragment (bf16 1.0 = 0x3F80) for the denominator MFMA
    short8 ones;
    {
        uintx4 uo = (uintx4){0x3F803F80u, 0x3F803F80u, 0x3F803F80u, 0x3F803F80u};
        ones = *(short8*)&uo;
    }

    const int lane8 = lane * 8;         // u16 offset of this lane within a frag row

    floatx4 acc[8];
    #pragma unroll
    for (int i = 0; i < 8; i++) acc[i] = (floatx4){0.f, 0.f, 0.f, 0.f};
    floatx4 acc_l = (floatx4){0.f, 0.f, 0.f, 0.f};   // denominators via MFMA

    const int ci  = m0 + l16;          // this lane's Q row (global index)
    const int qb4 = quad * 4;          // j sub-base within tile

    int jlo = i0 - (WIN - 1); if (jlo < 0) jlo = 0;
    const int jt_lo = jlo >> 5;
    const int jt_hi = (i0 + BR - 1) >> 5;

    const float SC2 = 0.08838834764831845f * 1.4426950408889634f;

    const int ch0 = w * 64 + lane;
    auto stage = [&](int bb, int jt) {
        const u16* kpt = kp  + ((size_t)(hk * NT + jt)) * TILE_CH * 8;
        const u16* vpt = vtp + ((size_t)(hk * NT + jt)) * TILE_CH * 8;
        #pragma unroll
        for (int it = 0; it < 2; it++) {
            int ch = ch0 + it * 256;
            __builtin_amdgcn_global_load_lds(
                (const __attribute__((address_space(1))) unsigned*)(kpt + ch * 8),
                (__attribute__((address_space(3))) unsigned*)(&Kt[bb][ch * 8]), 16, 0, 0);
            __builtin_amdgcn_global_load_lds(
                (const __attribute__((address_space(1))) unsigned*)(vpt + ch * 8),
                (__attribute__((address_space(3))) unsigned*)(&Vt[bb][ch * 8]), 16, 0, 0);
        }
    };

    stage(0, jt_lo);
    int bb = 0;

    for (int jt = jt_lo; jt <= jt_hi; jt++) {
        const int j0 = jt << 5;

        __syncthreads();   // drains this wave's global_load_lds (vmcnt(0))

        if (jt < jt_hi) stage(bb ^ 1, jt + 1);   // prefetch next tile

        // ---- swapped QK^T: ss[n][r] = S[j0 + n*16 + qb4 + r][ci], 8 mfma ----
        floatx4 ss[2];
        ss[0] = (floatx4){0.f, 0.f, 0.f, 0.f};
        ss[1] = (floatx4){0.f, 0.f, 0.f, 0.f};
        __builtin_amdgcn_s_setprio(1);
        #pragma unroll
        for (int kk = 0; kk < 4; kk++) {
            short8 kf0 = *(const short8*)(&Kt[bb][(kk << 9) + lane8]);          // instr kk
            short8 kf1 = *(const short8*)(&Kt[bb][((4 + kk) << 9) + lane8]);    // instr 4+kk
            ss[0] = __builtin_amdgcn_mfma_f32_16x16x32_bf16(kf0, qf[kk], ss[0], 0, 0, 0);
            ss[1] = __builtin_amdgcn_mfma_f32_16x16x32_bf16(kf1, qf[kk], ss[1], 0, 0, 0);
        }
        __builtin_amdgcn_s_setprio(0);

        // ---- early V-fragment loads: latency drains under softmax ----
        short8 vf[8];
        #pragma unroll
        for (int nf = 0; nf < 8; nf++)
            vf[nf] = *(const short8*)(&Vt[bb][(nf << 9) + lane8]);

        // ---- softmax (fixed max); P stays in registers ----
        float p[2][4];
        const bool interior = (j0 + (BC - 1) <= i0) && (j0 >= i0 + BR - WIN);
        if (interior) {
            #pragma unroll
            for (int n = 0; n < 2; n++)
                #pragma unroll
                for (int r = 0; r < 4; r++)
                    p[n][r] = exp2f(fmaf(ss[n][r], SC2, -FM));
        } else {
            const int dj = ci - j0;        // allowed: t <= dj && t > dj-WIN
            #pragma unroll
            for (int n = 0; n < 2; n++)
                #pragma unroll
                for (int r = 0; r < 4; r++) {
                    int t = n * 16 + qb4 + r;
                    bool a = (t <= dj) && (t > dj - WIN);
                    p[n][r] = a ? exp2f(fmaf(ss[n][r], SC2, -FM)) : 0.f;
                }
        }

        // ---- P -> A-fragment: interleave chain0/chain1 to match V's k-map ----
        uintx4 upf = (uintx4){cvt_pk(p[0][0], p[1][0]), cvt_pk(p[0][1], p[1][1]),
                              cvt_pk(p[0][2], p[1][2]), cvt_pk(p[0][3], p[1][3])};
        short8 pf = *(short8*)&upf;

        // ---- PV: 8 mfma + 1 denominator mfma (V already in registers) ----
        __builtin_amdgcn_s_setprio(1);
        acc_l = __builtin_amdgcn_mfma_f32_16x16x32_bf16(pf, ones, acc_l, 0, 0, 0);
        #pragma unroll
        for (int nf = 0; nf < 8; nf++) {
            acc[nf] = __builtin_amdgcn_mfma_f32_16x16x32_bf16(pf, vf[nf], acc[nf], 0, 0, 0);
        }
        __builtin_amdgcn_s_setprio(0);
        bb ^= 1;
    }

    // ---- epilogue: denominators already complete in acc_l[r] (no shuffles) ----
    const float sk2 = exp2f(fmaf(sg[h], 1.4426950408889634f, -FM));
    float inv_r[4];
    #pragma unroll
    for (int r = 0; r < 4; r++)
        inv_r[r] = 1.f / (acc_l[r] + sk2);
    #pragma unroll
    for (int nf = 0; nf < 8; nf++) {
        int d = nf * 16 + l16;
        #pragma unroll
        for (int r = 0; r < 4; r++) {
            int ig = m0 + qb4 + r;
            outg[((size_t)ig * HQ + h) * DH + d] = acc[nf][r] * inv_r[r];
        }
    }
}

// ---------------- fallback (used only if ws too small; champion verbatim) --------
__launch_bounds__(256, 4)
__global__ void fa_fallback(const float* __restrict__ qg,
                            const float* __restrict__ kg,
                            const float* __restrict__ vg,
                            const float* __restrict__ sg,
                            float* __restrict__ outg)
{
    __shared__ __align__(16) u16 Kt[BC * DH];
    __shared__ __align__(16) u16 Vt[DH * BC];
    __shared__ __align__(16) u16 Pb[BR * 40];

    const int tid  = threadIdx.x;
    const int w    = tid >> 6;
    const int lane = tid & 63;
    const int quad = lane >> 4;
    const int l16  = lane & 15;

    const int qb = blockIdx.x / HQ;
    const int h  = blockIdx.x % HQ;
    const int hk = h >> 2;
    const int i0 = qb * BR;
    const int m0 = i0 + w * 16;

    short8 qf[4];
    {
        const float* qrow = qg + ((size_t)(m0 + l16) * HQ + h) * DH;
        #pragma unroll
        for (int kk = 0; kk < 4; kk++) {
            const float* p = qrow + kk * 32 + quad * 8;
            floatx4 f0 = *(const floatx4*)p;
            floatx4 f1 = *(const floatx4*)(p + 4);
            uintx4 u = (uintx4){rne_pk(f0[0], f0[1]), rne_pk(f0[2], f0[3]),
                                rne_pk(f1[0], f1[1]), rne_pk(f1[2], f1[3])};
            qf[kk] = *(short8*)&u;
        }
    }

    floatx4 acc[8];
    #pragma unroll
    for (int i = 0; i < 8; i++) acc[i] = (floatx4){0.f, 0.f, 0.f, 0.f};
    float l_part[4] = {0.f, 0.f, 0.f, 0.f};

    int jlo = i0 - (WIN - 1); if (jlo < 0) jlo = 0;
    const int jt_lo = jlo >> 5;
    const int jt_hi = (i0 + BR - 1) >> 5;
    const float SC2 = 0.08838834764831845f * 1.4426950408889634f;

    for (int jt = jt_lo; jt <= jt_hi; jt++) {
        const int j0 = jt << 5;
        __syncthreads();
        #pragma unroll
        for (int it = 0; it < 2; it++) {
            int g   = tid + 256 * it;
            int row = g >> 4, cc = g & 15;
            int pc  = (row << 4) | (cc ^ (row & 7));
            const float* kpp = kg + ((size_t)(j0 + row) * HKV + hk) * DH + cc * 8;
            floatx4 f0 = *(const floatx4*)kpp;
            floatx4 f1 = *(const floatx4*)(kpp + 4);
            *(uintx4*)(&Kt[pc * 8]) =
                (uintx4){rne_pk(f0[0], f0[1]), rne_pk(f0[2], f0[3]),
                         rne_pk(f1[0], f1[1]), rne_pk(f1[2], f1[3])};
        }
        #pragma unroll
        for (int it = 0; it < 2; it++) {
            int g  = tid + 256 * it;
            int d  = g & 127, jc = g >> 7;
            const float* vp = vg + ((size_t)(j0 + jc * 8) * HKV + hk) * DH + d;
            float e0 = vp[0 * HKV * DH], e1 = vp[1 * HKV * DH];
            float e2 = vp[2 * HKV * DH], e3 = vp[3 * HKV * DH];
            float e4 = vp[4 * HKV * DH], e5 = vp[5 * HKV * DH];
            float e6 = vp[6 * HKV * DH], e7 = vp[7 * HKV * DH];
            int pc = (d << 2) | (jc ^ ((d >> 2) & 3));
            *(uintx4*)(&Vt[pc * 8]) =
                (uintx4){rne_pk(e0, e1), rne_pk(e2, e3), rne_pk(e4, e5), rne_pk(e6, e7)};
        }
        __syncthreads();

        floatx4 sc[2];
        sc[0] = (floatx4){0.f, 0.f, 0.f, 0.f};
        sc[1] = (floatx4){0.f, 0.f, 0.f, 0.f};
        #pragma unroll
        for (int kk = 0; kk < 4; kk++) {
            #pragma unroll
            for (int n = 0; n < 2; n++) {
                int row = n * 16 + l16;
                int cc  = kk * 4 + quad;
                int pc  = (row << 4) | (cc ^ (row & 7));
                short8 kf = *(const short8*)(&Kt[pc * 8]);
                sc[n] = __builtin_amdgcn_mfma_f32_16x16x32_bf16(qf[kk], kf, sc[n], 0, 0, 0);
            }
        }
        #pragma unroll
        for (int r = 0; r < 4; r++) {
            int   i_g = m0 + quad * 4 + r;
            int   jg0 = j0 + l16, jg1 = j0 + 16 + l16;
            bool  a0  = (jg0 <= i_g) && (i_g - jg0 < WIN);
            bool  a1  = (jg1 <= i_g) && (i_g - jg1 < WIN);
            float p0  = a0 ? exp2f(fmaf(sc[0][r], SC2, -FM)) : 0.f;
            float p1  = a1 ? exp2f(fmaf(sc[1][r], SC2, -FM)) : 0.f;
            l_part[r] += p0 + p1;
            int prow = w * 16 + quad * 4 + r;
            *(unsigned*)(&Pb[prow * 40 + 2 * l16]) = rne_pk(p0, p1);
        }
        {
            short8 pf = *(const short8*)(&Pb[(w * 16 + l16) * 40 + quad * 8]);
            #pragma unroll
            for (int nf = 0; nf < 8; nf++) {
                int dd = nf * 16 + l16;
                int qp = (dd << 2) | (quad ^ ((dd >> 2) & 3));
                short8 vf = *(const short8*)(&Vt[qp * 8]);
                acc[nf] = __builtin_amdgcn_mfma_f32_16x16x32_bf16(pf, vf, acc[nf], 0, 0, 0);
            }
        }
    }

    const float sk2 = exp2f(fmaf(sg[h], 1.4426950408889634f, -FM));
    float inv[4];
    #pragma unroll
    for (int r = 0; r < 4; r++) {
        float l = l_part[r];
        #pragma unroll
        for (int off = 1; off < 16; off <<= 1)
            l += __shfl_xor(l, off);
        inv[r] = 1.f / (l + sk2);
    }
    #pragma unroll
    for (int nf = 0; nf < 8; nf++) {
        int d = nf * 16 + l16;
        #pragma unroll
        for (int r = 0; r < 4; r++) {
            int ig = m0 + quad * 4 + r;
            outg[((size_t)ig * HQ + h) * DH + d] = acc[nf][r] * inv[r];
        }
    }
}

extern "C" void kernel_launch(void* const* d_in, const int* in_sizes, int n_in,
                              void* d_out, int out_size, void* d_ws, size_t ws_size,
                              hipStream_t stream) {
    const float* q  = (const float*)d_in[0];
    const float* k  = (const float*)d_in[1];
    const float* v  = (const float*)d_in[2];
    const float* sk = (const float*)d_in[3];
    float* out = (float*)d_out;

    const size_t tile_elems = (size_t)HKV * NT * TILE_CH * 8;   // u16 elems per tensor
    const size_t need = 2 * tile_elems * sizeof(u16);           // 8 MB

    if (ws_size >= need) {
        u16* kp  = (u16*)d_ws;
        u16* vtp = kp + tile_elems;
        pack_kv<<<dim3(HKV * NT), 256, 0, stream>>>(k, v, kp, vtp);
        fa_kernel<<<dim3((S_LEN / BR) * HQ), 256, 0, stream>>>(q, kp, vtp, sk, out);
    } else {
        fa_fallback<<<dim3((S_LEN / BR) * HQ), 256, 0, stream>>>(q, k, v, sk, out);
    }
}